// Round 6
// baseline (259.751 us; speedup 1.0000x reference)
//
#include <hip/hip_runtime.h>

// EdgeConv: B=32, N=2048, D=16, PCD=2, K_NN=16, FILTERS=64
// out[b,n,0:64]  = max(y_n, max_k y_{nn_k} - y_n) + b   where y = x@W (linearity)
// out[b,n,64:80] = x[b,n,:]
//
// R16 = R15 resubmitted verbatim (R15 hit an infra failure, no kernel signal).
// R15 = R11 (passed, absmax 0.03125) with PER-QUERY CODE BYTE-IDENTICAL,
// restructured to 512-thread blocks for occupancy:
//   - staging, sqs[], sqn=sqs[q], pass-1 packed-f16 (sa=sqs[m]), +2-ulp16
//     threshold, pass-2 verbatim f32 screen (sqs[m]), finish T/tie logic:
//     all byte-exact R11. (R12/R13/R14 all removed sqs+used a float2 cast
//     staging load and failed bit-identically 0.453125 -> that delta reverted.)
//   - block = 512 thr = 8 waves = {2 query-subgroups sg} x {4 splits s};
//     128 queries/block share ONE pts+sqs staging. Grid 1024 -> 512 blocks.
//   - LDS 56320 B -> 2 blocks/CU = 16 waves/CU (was 3 blocks = 12), grid
//     512 = 2x256 CUs -> SINGLE generation (was 768+256 two-generation tail).

#define B_  32
#define N_  2048
#define D_  16
#define F_  64
#define K_  16
#define OUTD (F_ + D_)   // 80
#define NQB 128          // queries per block (2 subgroups of 64)
#define NS  4            // candidate splits
#define SPLIT (N_ / NS)  // 512
#define CAP 24           // survivor cap per (query, split)

typedef _Float16 h2 __attribute__((ext_vector_type(2)));

static __device__ __forceinline__ h2 h2min(h2 a, h2 b) { return __builtin_elementwise_min(a, b); }
static __device__ __forceinline__ h2 h2max(h2 a, h2 b) { return __builtin_elementwise_max(a, b); }
static __device__ __forceinline__ _Float16 hmn(_Float16 a, _Float16 b) { return __builtin_elementwise_min(a, b); }
static __device__ __forceinline__ _Float16 hmx(_Float16 a, _Float16 b) { return __builtin_elementwise_max(a, b); }
static __device__ __forceinline__ unsigned short h2b(_Float16 h) { return __builtin_bit_cast(unsigned short, h); }
static __device__ __forceinline__ _Float16 b2h(unsigned short b) { return __builtin_bit_cast(_Float16, b); }

// insert ordered pair y0<=y1 into ascending sorted-16 (drop 2 largest) — exact
static __device__ __forceinline__ void pair_ins(_Float16 (&k)[16], _Float16 y0, _Float16 y1) {
#pragma unroll
    for (int j = 15; j >= 2; --j)
        k[j] = hmn(hmn(k[j], hmx(k[j - 1], y0)), hmx(k[j - 2], y1));
    k[1] = hmn(hmn(k[1], hmx(k[0], y0)), y1);
    k[0] = hmn(k[0], y0);
}

// ---------------- K1: Y = X * W  (bias folded into fused kernel) ------------
__global__ __launch_bounds__(256) void proj_kernel(const float* __restrict__ x,
                                                   const float* __restrict__ W,
                                                   float* __restrict__ Y) {
    __shared__ float Ws[D_ * F_];     // 4 KB
    __shared__ float xs[16][D_];      // 1 KB
    const int t = threadIdx.x;
    for (int i = t; i < D_ * F_; i += 256) Ws[i] = W[i];
    const int p0 = blockIdx.x * 16;
    ((float*)xs)[t] = x[(size_t)p0 * D_ + t];   // coalesced 1 KB
    __syncthreads();
    const int w = t >> 6, f = t & 63;
#pragma unroll
    for (int i = 0; i < 4; i++) {
        const int pw = w * 4 + i;
        float acc = 0.f;
#pragma unroll
        for (int d = 0; d < D_; d++) acc = fmaf(xs[pw][d], Ws[d * F_ + f], acc);
        Y[(size_t)(p0 + pw) * F_ + f] = acc;
    }
}

// ---------------- K2: exact 16-NN + fused conv-max-pool epilogue ------------
__global__ __launch_bounds__(512, 2) void knn_kernel(const float* __restrict__ x,
                                                     const float* __restrict__ bias,
                                                     const float* __restrict__ Y,
                                                     float* __restrict__ out) {
    __shared__ float2 pts[N_];                       // 16384 B
    __shared__ float  sqs[N_];                       // 8192 B  (R11 verbatim)
    // overlay: arr32 (13824 B) lives [barrier2, barrier3); survb [barrier3,..)
    __shared__ __align__(16) char region[NS * NQB * CAP * 2];   // 24576 B
    __shared__ unsigned short idxL[NQB][18];         // 4608 B (stride 36 B)
    __shared__ int   scnt[NS][NQB];                  // 2048 B
    __shared__ float TubA[NQB];                      // 512 B  => 56320 B total

    unsigned (*arr32)[NQB][9] = (unsigned (*)[NQB][9])region;                  // [NS-1][NQB][9]
    unsigned short (*survb)[NQB][CAP] = (unsigned short (*)[NQB][CAP])region;  // [NS][NQB][CAP]

    const int b = blockIdx.x >> 4;                 // 16 blocks per batch
    const int qbase = (blockIdx.x & 15) * NQB;
    const int t = threadIdx.x;
    const int w8 = t >> 6;                         // wave id 0..7
    const int s  = w8 & 3;                         // split id
    const int sg = w8 >> 2;                        // query subgroup 0/1
    const int qi = t & 63;
    const int qloc = sg * 64 + qi;                 // block-local query 0..127
    const int q = qbase + qloc;                    // batch-local point id

    // ---- staging: R11 BYTE-EXACT (scalar loads, sqs staged) ----
    const float* xb = x + (size_t)b * N_ * D_;
    for (int m = t; m < N_; m += 512) {
        float2 p = make_float2(xb[m * D_ + 0], xb[m * D_ + 1]);
        pts[m] = p;
        sqs[m] = __fadd_rn(__fmul_rn(p.x, p.x), __fmul_rn(p.y, p.y));
    }
    __syncthreads();                               // barrier 1

    const float2 qp = pts[q];
    const float sqn = sqs[q];
    const float n2x = -2.0f * qp.x, n2y = -2.0f * qp.y;   // exact

    // ---- pass 1 (wave = (sg,s)): packed-f16 dual sorted-16 over 512 cands
    h2 key2[16];
    const _Float16 hinf = b2h((unsigned short)0x7C00);
#pragma unroll
    for (int j = 0; j < 16; ++j) key2[j] = (h2){hinf, hinf};

    const int m0 = s * SPLIT, m1 = m0 + SPLIT;
#pragma unroll 4
    for (int m = m0; m < m1; m += 2) {
        float2 pa = pts[m];     float sa = sqs[m];
        float2 pb = pts[m + 1]; float sb = sqs[m + 1];
        float da = __fmaf_rn(n2y, pa.y, __fmaf_rn(n2x, pa.x, sqn + sa));
        float db = __fmaf_rn(n2y, pb.y, __fmaf_rn(n2x, pb.x, sqn + sb));
        h2 v = __builtin_bit_cast(h2, __builtin_amdgcn_cvt_pkrtz(da, db));
        // single-insert into both packed lists: reads OLD key2[j-1] (descending)
#pragma unroll
        for (int j = 15; j >= 1; --j)
            key2[j] = h2min(key2[j], h2max(key2[j - 1], v));
        key2[0] = h2min(key2[0], v);
    }

    // merge odd-list into even-list -> per-split sorted-16 (f16 scalar)
    _Float16 keyl[16];
#pragma unroll
    for (int j = 0; j < 16; ++j) keyl[j] = key2[j].x;
#pragma unroll
    for (int tt = 0; tt < 8; ++tt) pair_ins(keyl, key2[2 * tt].y, key2[2 * tt + 1].y);

    if (s > 0) {
#pragma unroll
        for (int tt = 0; tt < 8; ++tt)
            arr32[s - 1][qloc][tt] =
                (unsigned)h2b(keyl[2 * tt]) | ((unsigned)h2b(keyl[2 * tt + 1]) << 16);
    }
    __syncthreads();                               // barrier 2

    // ---- merge (waves s==0, i.e. waves 0 and 4): global f16 16th -> T_ub
    if (s == 0) {
        for (int ss = 0; ss < NS - 1; ++ss) {
#pragma unroll
            for (int tt = 0; tt < 8; ++tt) {
                unsigned w32 = arr32[ss][qloc][tt];
                pair_ins(keyl, b2h((unsigned short)(w32 & 0xffffu)),
                               b2h((unsigned short)(w32 >> 16)));
            }
        }
        // T16 = RTZ(exact 16th smallest); +2 bits >= 1 f16 ulp margin (R11)
        float tub = (float)b2h((unsigned short)(h2b(keyl[15]) + 2));
        TubA[qloc] = fmaxf(tub, 7e-5f);            // denormal-flush guard
    }
    __syncthreads();                               // barrier 3 (arr32 dead)

    // ---- pass 2: VERBATIM f32 survivors d < Tub, index-ascending (R11)
    const float Tub = TubA[qloc];
    int sc = 0;
#pragma unroll 2
    for (int m = m0; m < m1; ++m) {
        float2 p = pts[m];
        float dot = __fmaf_rn(qp.y, p.y, __fmul_rn(qp.x, p.x));
        float d   = __fsub_rn(__fadd_rn(sqn, sqs[m]), __fmul_rn(2.f, dot));
        if (d < Tub) { if (sc < CAP) survb[s][qloc][sc] = (unsigned short)m; sc++; }
    }
    scnt[s][qloc] = (sc < CAP) ? sc : CAP;
    __syncthreads();                               // barrier 4

    // ---- finish (waves s==0, lane qi -> query qloc): exact T + ordered emit
    if (s == 0) {
        float key[16];
#pragma unroll
        for (int j = 0; j < 16; ++j) key[j] = INFINITY;
        for (int ss = 0; ss < NS; ++ss) {
            int n = scnt[ss][qloc];
            for (int j = 0; j < n; ++j) {
                int m = (int)survb[ss][qloc][j];
                float2 p = pts[m];
                float dot = __fmaf_rn(qp.y, p.y, __fmul_rn(qp.x, p.x));
                float d   = __fsub_rn(__fadd_rn(sqn, sqs[m]), __fmul_rn(2.f, dot));
#pragma unroll
                for (int jj = 15; jj >= 1; --jj)
                    key[jj] = fminf(key[jj], fmaxf(key[jj - 1], d));
                key[0] = fminf(key[0], d);
            }
        }
        const float T = key[15];                   // exact global 16th smallest
        int w = 0;
        for (int ss = 0; ss < NS; ++ss) {          // strict d<T, global idx order
            int n = scnt[ss][qloc];
            for (int j = 0; j < n; ++j) {
                int m = (int)survb[ss][qloc][j];
                float2 p = pts[m];
                float dot = __fmaf_rn(qp.y, p.y, __fmul_rn(qp.x, p.x));
                float d   = __fsub_rn(__fadd_rn(sqn, sqs[m]), __fmul_rn(2.f, dot));
                if (d < T && w < K_) idxL[qloc][w++] = (unsigned short)m;
            }
        }
        for (int ss = 0; ss < NS && w < K_; ++ss) { // ties d==T, idx order
            int n = scnt[ss][qloc];
            for (int j = 0; j < n && w < K_; ++j) {
                int m = (int)survb[ss][qloc][j];
                float2 p = pts[m];
                float dot = __fmaf_rn(qp.y, p.y, __fmul_rn(qp.x, p.x));
                float d   = __fsub_rn(__fadd_rn(sqn, sqs[m]), __fmul_rn(2.f, dot));
                if (d == T) idxL[qloc][w++] = (unsigned short)m;
            }
        }
        // defensive (dead if selection correct): bound any residual bug
        while (w < K_) idxL[qloc][w++] = (unsigned short)q;
    }
    __syncthreads();                               // barrier 5

    // ---- fused pool epilogue: wave w8 handles queries w8*16 .. w8*16+15
    const int f = qi;                              // lane = filter (64)
    const float bf = bias[f];
    const float* Yb = Y + (size_t)b * N_ * F_;
    for (int i = 0; i < 16; i++) {
        const int qq = w8 * 16 + i;                // block-local query id 0..127
        const int gq = qbase + qq;                 // batch-local point id
        const float yn = Yb[(size_t)gq * F_ + f];
        float M = -INFINITY;
#pragma unroll
        for (int k = 0; k < K_; k++) {
            int m = (int)idxL[qq][k];              // wave-uniform -> broadcast
            M = fmaxf(M, Yb[(size_t)m * F_ + f]);  // coalesced 256B row
        }
        const size_t pb = (size_t)b * N_ + gq;
        out[pb * OUTD + f] = fmaxf(yn, M - yn) + bf;
        if (f < D_) out[pb * OUTD + F_ + f] = xb[(size_t)gq * D_ + f];
    }
}

extern "C" void kernel_launch(void* const* d_in, const int* in_sizes, int n_in,
                              void* d_out, int out_size, void* d_ws, size_t ws_size,
                              hipStream_t stream) {
    const float* x    = (const float*)d_in[0];
    const float* W    = (const float*)d_in[1];
    const float* bias = (const float*)d_in[2];
    float* out = (float*)d_out;

    float* Y = (float*)d_ws;                       // 16.78 MB scratch

    proj_kernel<<<B_ * N_ / 16, 256, 0, stream>>>(x, W, Y);
    knn_kernel <<<B_ * (N_ / NQB), 512, 0, stream>>>(x, bias, Y, out);
}